// Round 4
// baseline (669.970 us; speedup 1.0000x reference)
//
#include <hip/hip_runtime.h>

// ODEFunc CNF dynamics, B=1e6 rows:
//   h1 = elu(W1 z + b1); [h2|u2|v2] = W2 [h1|u|v]; out01 = W3 elu(h2) + b3;
//   trace = W3[0,:]·(elu'(h2)*u2) + W3[1,:]·(elu'(h2)*v2); out[:,2] = -trace
//
// R4: one thread per row, k-TILED to kill the AGPR problem.
// History: R1 (192-float arrays, cap 128) -> AGPR shuffle, 349us.
//          R2 (no bounds, cap 64) -> scratch, 5632us.
//          R3 (cap 512 requested) -> allocator still split 104 arch + ~150 AGPR
//              at its 2-wave target; v_accvgpr_read doubled VALU work -> 441us.
// Structural fix: never hold 192 floats. Outer loop over 4 k-tiles of 16;
// acc/d0/d1[16] (48 regs) live per tile; layer-1 h/u/v streamed in j-chunks
// of 8 (24 regs), RECOMPUTED per k-tile (15% extra VALU, buys ~90-reg state).
// asm fence on z0/z1 per k-tile defeats LICM re-hoisting layer 1.
// Weights via wave-uniform s_load (SMEM pipe, SGPR fma operand) - R3-proven.

__global__ __launch_bounds__(256, 4)
void odefunc_kernel(const float* __restrict__ zin,
                    const float* __restrict__ W1, const float* __restrict__ b1,
                    const float* __restrict__ W2, const float* __restrict__ b2,
                    const float* __restrict__ W3, const float* __restrict__ b3,
                    float* __restrict__ out, int B)
{
    int r = blockIdx.x * blockDim.x + threadIdx.x;
    if (r >= B) return;

    float z0 = zin[3 * r + 0];
    float z1 = zin[3 * r + 1];

    float out0 = b3[0], out1 = b3[1], tr = 0.f;

#pragma unroll 1   // keep kt rolled: acc state stays at 16, not 64
    for (int kt = 0; kt < 4; ++kt) {
        // Opaque copies of z: blocks LICM/CSE of the layer-1 recompute
        // across kt iterations (otherwise 192 values get hoisted -> AGPRs).
        float z0w = z0, z1w = z1;
        asm volatile("" : "+v"(z0w), "+v"(z1w));

        float acc[16], d0[16], d1[16];
#pragma unroll
        for (int k = 0; k < 16; ++k) {
            acc[k] = b2[kt * 16 + k];   // uniform -> s_load
            d0[k] = 0.f;
            d1[k] = 0.f;
        }

#pragma unroll
        for (int jc = 0; jc < 8; ++jc) {
            // ---- layer 1 for j in [8*jc, 8*jc+8) ----
            float h[8], u[8], v[8];
#pragma unroll
            for (int jj = 0; jj < 8; ++jj) {
                int j = jc * 8 + jj;
                float w0 = W1[2 * j + 0];   // uniform -> s_load
                float w1 = W1[2 * j + 1];
                float a = fmaf(w0, z0w, fmaf(w1, z1w, b1[j]));
                float ex = __expf(fminf(a, 0.f));   // clamp avoids inf path
                bool pos = a > 0.f;
                h[jj] = pos ? a : (ex - 1.f);       // elu
                float g = pos ? 1.f : ex;           // elu'
                u[jj] = g * w0;
                v[jj] = g * w1;
            }
            // ---- partial layer 2: 16 k x 8 j x 3 mats ----
#pragma unroll
            for (int k = 0; k < 16; ++k) {
                const float* wr = W2 + (kt * 16 + k) * 64 + jc * 8;  // uniform
#pragma unroll
                for (int jj = 0; jj < 8; ++jj) {
                    float w = wr[jj];               // SGPR operand of v_fma
                    acc[k] = fmaf(w, h[jj], acc[k]);
                    d0[k]  = fmaf(w, u[jj], d0[k]);
                    d1[k]  = fmaf(w, v[jj], d1[k]);
                }
            }
        }

        // ---- elu + layer-3 fold for this k-tile ----
#pragma unroll
        for (int k = 0; k < 16; ++k) {
            float a = acc[k];
            float ex = __expf(fminf(a, 0.f));
            bool pos = a > 0.f;
            float hh = pos ? a : (ex - 1.f);
            float g  = pos ? 1.f : ex;
            float w30 = W3[kt * 16 + k];            // W3[0,k]
            float w31 = W3[64 + kt * 16 + k];       // W3[1,k]
            out0 = fmaf(w30, hh, out0);
            out1 = fmaf(w31, hh, out1);
            tr = fmaf(w30, g * d0[k], fmaf(w31, g * d1[k], tr));
        }
    }

    out[3 * r + 0] = out0;
    out[3 * r + 1] = out1;
    out[3 * r + 2] = -tr;
}

extern "C" void kernel_launch(void* const* d_in, const int* in_sizes, int n_in,
                              void* d_out, int out_size, void* d_ws, size_t ws_size,
                              hipStream_t stream) {
    // d_in: 0=t(unused) 1=z_and_logp 2=W1 3=b1 4=W2 5=b2 6=W3 7=b3
    const float* zin = (const float*)d_in[1];
    const float* W1  = (const float*)d_in[2];
    const float* b1  = (const float*)d_in[3];
    const float* W2  = (const float*)d_in[4];
    const float* b2  = (const float*)d_in[5];
    const float* W3  = (const float*)d_in[6];
    const float* b3  = (const float*)d_in[7];
    float* out = (float*)d_out;

    int B = in_sizes[1] / 3;
    int grid = (B + 255) / 256;
    odefunc_kernel<<<grid, 256, 0, stream>>>(zin, W1, b1, W2, b2, W3, b3, out, B);
}